// Round 18
// baseline (1063.472 us; speedup 1.0000x reference)
//
#include <hip/hip_runtime.h>
#include <hip/hip_bf16.h>
#include <cstddef>

#define BB 16
#define LL 2048
#define DM 128
#define DI 256
#define DS 16
#define MP (BB*LL)          // 32768 positions
#define NSEG 64
#define SEGLEN (LL/NSEG)    // 32
#define YSTR 268            // ybuf LDS row stride (dwords)
#define XSTR 40             // sx LDS row stride (floats)

typedef __attribute__((ext_vector_type(8))) short bf16x8;
typedef __attribute__((ext_vector_type(4))) short bf16x4s;
typedef __attribute__((ext_vector_type(8))) unsigned int ux8;
typedef __attribute__((ext_vector_type(4))) float f32x4;
typedef __hip_bfloat16 bf16;
typedef unsigned int uint;

__device__ inline void bf16split(float x, bf16& h, bf16& l) {
  h = __float2bfloat16(x);
  l = __float2bfloat16(x - __bfloat162float(h));
}
__device__ inline float bf2f(bf16 v) { return __bfloat162float(v); }
__device__ inline void split_bits2(float x, short& hs, short& ls) {
  bf16 hb = __float2bfloat16(x);
  bf16 lb = __float2bfloat16(x - __bfloat162float(hb));
  hs = *(short*)&hb;
  ls = *(short*)&lb;
}
__device__ inline float sigm(float x) {
  return __builtin_amdgcn_rcpf(1.f + __expf(-x));
}
__device__ inline uint pk2(short h, short l) {
  return (uint)(unsigned short)h | ((uint)(unsigned short)l << 16);
}
__device__ inline uint pack_hl(float x) {
  short hs, ls; split_bits2(x, hs, ls);
  return pk2(hs, ls);
}
__device__ inline float unpack_hl(uint w) {
  return __uint_as_float(w << 16) + __uint_as_float(w & 0xffff0000u);
}

// ---------------------------------------------------------------------------
// in_proj: block = 32 positions x 256 cols. Packed dword outputs, no LDS.
// ---------------------------------------------------------------------------
__global__ __launch_bounds__(256, 4) void gemm_inproj(
    const bf16* __restrict__ Ah, const bf16* __restrict__ Al,
    const bf16* __restrict__ Wh, const bf16* __restrict__ Wl,
    uint* __restrict__ xm_pk, uint* __restrict__ zs_pk) {
  int tid = threadIdx.x;
  int wave = tid >> 6, lane = tid & 63;
  int r16 = lane & 15, quad = lane >> 4;
  int bid = blockIdx.x;
  int nh = bid & 1, mb = bid >> 1;
  int m0 = mb * 32;
  int n0 = nh * 256 + wave * 64;
  size_t arow[2], brow[4];
#pragma unroll
  for (int i = 0; i < 2; i++)
    arow[i] = (size_t)(m0 + i * 16 + r16) * DM + quad * 8;
#pragma unroll
  for (int j = 0; j < 4; j++)
    brow[j] = (size_t)(n0 + j * 16 + r16) * DM + quad * 8;
  f32x4 acc[2][4] = {};
#pragma unroll
  for (int kk = 0; kk < 4; kk++) {
    int ko = kk * 32;
    bf16x8 ah[2], al[2], bh[4], bl[4];
#pragma unroll
    for (int i = 0; i < 2; i++) {
      ah[i] = *(const bf16x8*)(Ah + arow[i] + ko);
      al[i] = *(const bf16x8*)(Al + arow[i] + ko);
    }
#pragma unroll
    for (int j = 0; j < 4; j++) {
      bh[j] = *(const bf16x8*)(Wh + brow[j] + ko);
      bl[j] = *(const bf16x8*)(Wl + brow[j] + ko);
    }
#pragma unroll
    for (int i = 0; i < 2; i++)
#pragma unroll
      for (int j = 0; j < 4; j++) {
        acc[i][j] = __builtin_amdgcn_mfma_f32_16x16x32_bf16(ah[i], bh[j], acc[i][j], 0, 0, 0);
        acc[i][j] = __builtin_amdgcn_mfma_f32_16x16x32_bf16(ah[i], bl[j], acc[i][j], 0, 0, 0);
        acc[i][j] = __builtin_amdgcn_mfma_f32_16x16x32_bf16(al[i], bh[j], acc[i][j], 0, 0, 0);
      }
  }
  bool isz = (n0 >= 256);
  uint* dst = isz ? zs_pk : xm_pk;
  int cb = n0 & 255;
#pragma unroll
  for (int i = 0; i < 2; i++)
#pragma unroll
    for (int j = 0; j < 4; j++)
#pragma unroll
      for (int r = 0; r < 4; r++) {
        int row = m0 + i * 16 + quad * 4 + r;
        int col = cb + j * 16 + r16;
        float v = acc[i][j][r];
        if (isz) v *= sigm(v);
        dst[(size_t)row * DI + col] = pack_hl(v);
      }
}

// ---------------------------------------------------------------------------
// x_proj with fused conv+SiLU. Wave owns a distinct 16-row m-tile x 48 cols.
// ---------------------------------------------------------------------------
__global__ __launch_bounds__(256, 2) void gemm_conv(
    const uint* __restrict__ xm_pk,
    const bf16* __restrict__ Wh, const bf16* __restrict__ Wl,
    const float* __restrict__ cw, const float* __restrict__ cb,
    float* __restrict__ C, uint* __restrict__ u_pk) {
  __shared__ float scw[DI * 4 + DI];
  int tid = threadIdx.x;
  {
    float4 w4 = *(const float4*)(cw + tid * 4);
    *(float4*)(scw + tid * 4) = w4;
    scw[DI * 4 + tid] = cb[tid];
  }
  __syncthreads();
  int wave = tid >> 6, lane = tid & 63;
  int r16 = lane & 15, quad = lane >> 4;
  int m0 = blockIdx.x * 64 + wave * 16;
  int m = m0 + r16;
  int l = m & (LL - 1);
  size_t rb[4]; float msk[3];
#pragma unroll
  for (int t = 0; t < 3; t++) {
    msk[t] = (l >= (3 - t)) ? 1.f : 0.f;
    int mr = m - 3 + t; if (mr < 0) mr = 0;
    rb[t] = (size_t)mr * DI;
  }
  rb[3] = (size_t)m * DI;
  size_t brow[3];
#pragma unroll
  for (int j = 0; j < 3; j++)
    brow[j] = (size_t)(j * 16 + r16) * DI + quad * 8;
  f32x4 acc[3] = {};
#pragma unroll
  for (int kk = 0; kk < 8; kk++) {
    int ko = quad * 8 + kk * 32;
    bf16x8 ah, al, bh[3], bl[3];
    ux8 xv[4];
#pragma unroll
    for (int t = 0; t < 4; t++)
      xv[t] = *(const ux8*)(xm_pk + rb[t] + ko);
#pragma unroll
    for (int e = 0; e < 8; e++) {
      int k = ko + e;
      float x0 = unpack_hl(xv[0][e]) * msk[0];
      float x1 = unpack_hl(xv[1][e]) * msk[1];
      float x2 = unpack_hl(xv[2][e]) * msk[2];
      float x3 = unpack_hl(xv[3][e]);
      float c0 = scw[DI * 4 + k] + scw[k*4]*x0 + scw[k*4+1]*x1 + scw[k*4+2]*x2 + scw[k*4+3]*x3;
      float u = c0 * sigm(c0);
      short hs, ls; split_bits2(u, hs, ls);
      ah[e] = hs; al[e] = ls;
    }
    {
      size_t g = rb[3] + ko;
      uint4 p0, p1;
      p0.x = pk2(ah[0], al[0]); p0.y = pk2(ah[1], al[1]);
      p0.z = pk2(ah[2], al[2]); p0.w = pk2(ah[3], al[3]);
      p1.x = pk2(ah[4], al[4]); p1.y = pk2(ah[5], al[5]);
      p1.z = pk2(ah[6], al[6]); p1.w = pk2(ah[7], al[7]);
      *(uint4*)(u_pk + g) = p0;
      *(uint4*)(u_pk + g + 4) = p1;
    }
#pragma unroll
    for (int j = 0; j < 3; j++) {
      bh[j] = *(const bf16x8*)(Wh + brow[j] + kk * 32);
      bl[j] = *(const bf16x8*)(Wl + brow[j] + kk * 32);
    }
#pragma unroll
    for (int j = 0; j < 3; j++) {
      acc[j] = __builtin_amdgcn_mfma_f32_16x16x32_bf16(ah, bh[j], acc[j], 0, 0, 0);
      acc[j] = __builtin_amdgcn_mfma_f32_16x16x32_bf16(ah, bl[j], acc[j], 0, 0, 0);
      acc[j] = __builtin_amdgcn_mfma_f32_16x16x32_bf16(al, bh[j], acc[j], 0, 0, 0);
    }
  }
#pragma unroll
  for (int j = 0; j < 3; j++)
#pragma unroll
    for (int r = 0; r < 4; r++) {
      int row = m0 + quad * 4 + r;
      int col = j * 16 + r16;
      C[(size_t)row * 64 + col] = acc[j][r];
    }
}

// ---------------------------------------------------------------------------
// Encoder (K=12, direct)
// ---------------------------------------------------------------------------
__global__ __launch_bounds__(256) void encoder_kernel(const float* __restrict__ x,
    const float* __restrict__ ew, const float* __restrict__ eb,
    float* __restrict__ h) {
  int idx = blockIdx.x * 256 + threadIdx.x;
  int d = idx & 127, m = idx >> 7;
  float acc = eb[d];
#pragma unroll
  for (int c = 0; c < 12; c++) acc += x[m * 12 + c] * ew[d * 12 + c];
  h[idx] = acc;
}

// ---------------------------------------------------------------------------
// Weight splits
// ---------------------------------------------------------------------------
__global__ void split_w(const float* __restrict__ src, bf16* __restrict__ hi,
                        bf16* __restrict__ lo, int n) {
  int i = blockIdx.x * 256 + threadIdx.x;
  if (i < n) bf16split(src[i], hi[i], lo[i]);
}

__global__ void split_w_pad(const float* __restrict__ src, bf16* __restrict__ hi,
                            bf16* __restrict__ lo) {
  int i = blockIdx.x * 256 + threadIdx.x;   // < 4*64*256
  int l = i >> 14, rem = i & 16383, r = rem >> 8, k = rem & 255;
  float v = (r < 40) ? src[l * 10240 + r * 256 + k] : 0.f;
  bf16split(v, hi[i], lo[i]);
}

// ---------------------------------------------------------------------------
// RMSNorm (layer-0 input only)
// ---------------------------------------------------------------------------
__global__ __launch_bounds__(256) void rmsnorm_kernel(const float* __restrict__ x,
    const float* __restrict__ w, bf16* __restrict__ oh, bf16* __restrict__ ol) {
  int lane = threadIdx.x & 63;
  int pos = blockIdx.x * 4 + (threadIdx.x >> 6);
  const float* row = x + (size_t)pos * DM;
  float v0 = row[lane], v1 = row[lane + 64];
  float ss = v0 * v0 + v1 * v1;
#pragma unroll
  for (int off = 1; off < 64; off <<= 1) ss += __shfl_xor(ss, off);
  float sc = rsqrtf(ss * (1.f / DM) + 1e-5f);
  float a = v0 * sc * w[lane], b = v1 * sc * w[lane + 64];
  size_t o = (size_t)pos * DM;
  bf16split(a, oh[o + lane], ol[o + lane]);
  bf16split(b, oh[o + lane + 64], ol[o + lane + 64]);
}

// ---------------------------------------------------------------------------
// Scan helpers
// ---------------------------------------------------------------------------
__device__ inline float softplus_f(float a) {
  float r = __logf(1.f + __expf(a));
  return a > 15.f ? a : r;
}

__device__ inline void make_powers(float r, float* rp) {
  rp[0] = r;
#pragma unroll
  for (int n = 1; n < 16; n++) {
    int a = (n + 1) >> 1, b = (n + 1) - a;
    rp[n] = rp[a - 1] * rp[b - 1];
  }
}

__device__ inline bool a_is_integer(const float* A_log, int d) {
  bool ok = true;
#pragma unroll
  for (int n = 0; n < DS; n++) {
    float Ad = -__expf(A_log[d * DS + n]);
    ok = ok && (fabsf(Ad + (float)(n + 1)) < 1e-3f);
  }
  return ok;
}

// load 32 rows x 40 cols of xdbl (cols 0..39) into LDS, stride XSTR
__device__ inline void load_sx(float* sx, const float* xdbl, size_t rbase, int tid) {
#pragma unroll
  for (int j = 0; j < 2; j++) {
    int idx = j * 256 + tid;       // < 320 = 32 rows x 10 float4
    if (idx < 320) {
      int row = idx / 10, c = idx % 10;
      *(float4*)(sx + row * XSTR + c * 4) = *(const float4*)(xdbl + rbase + row * 64 + c * 4);
    }
  }
}

template<bool FAST>
__device__ inline void scan1_body(int s, int b, int d, const float* sx,
    const uint* __restrict__ u_pk,
    const float* __restrict__ dtw, const float* __restrict__ dtb,
    const float* __restrict__ A_log,
    float* __restrict__ sega, float* __restrict__ segh) {
  float wdt[8];
#pragma unroll
  for (int j = 0; j < 8; j++) wdt[j] = dtw[d * 8 + j];
  float bdt = dtb[d];
  float h[DS];
#pragma unroll
  for (int n = 0; n < DS; n++) h[n] = 0.f;
  float R = 1.f;
  float ap[DS];
  if (!FAST) {
#pragma unroll
    for (int n = 0; n < DS; n++) ap[n] = 1.f;
  }
  size_t base = (size_t)b * LL + (size_t)s * SEGLEN;
  const uint* up = u_pk + base * DI + d;
  // burst-prefetch u in groups of 8 steps
  for (int t0 = 0; t0 < SEGLEN; t0 += 8) {
    uint ub[8];
#pragma unroll
    for (int q = 0; q < 8; q++) ub[q] = up[(size_t)q * DI];
    up += 8 * DI;
#pragma unroll
    for (int q = 0; q < 8; q++) {
      int t = t0 + q;
      const float* xr = sx + t * XSTR;
      float dt = bdt;
#pragma unroll
      for (int j = 0; j < 8; j++) dt += xr[j] * wdt[j];
      float dl = softplus_f(dt);
      float u = unpack_hl(ub[q]);
      float du = dl * u;
      if (FAST) {
        float rp[DS];
        make_powers(__expf(-dl), rp);
        R *= rp[0];
#pragma unroll
        for (int n = 0; n < DS; n++) h[n] = fmaf(rp[n], h[n], du * xr[8 + n]);
      } else {
#pragma unroll
        for (int n = 0; n < DS; n++) {
          float dA = __expf(dl * (-__expf(A_log[d * DS + n])));
          h[n] = fmaf(dA, h[n], du * xr[8 + n]);
          ap[n] *= dA;
        }
      }
    }
  }
  if (FAST) make_powers(R, ap);
  size_t o = ((size_t)s * 4096 + b * 256 + d) * DS;
#pragma unroll
  for (int j = 0; j < 4; j++) {
    *(float4*)(sega + o + 4 * j) = make_float4(ap[4*j], ap[4*j+1], ap[4*j+2], ap[4*j+3]);
    *(float4*)(segh + o + 4 * j) = make_float4(h[4*j], h[4*j+1], h[4*j+2], h[4*j+3]);
  }
}

__global__ __launch_bounds__(256, 4) void scan_phase1(
    const uint* __restrict__ u_pk, const float* __restrict__ xdbl,
    const float* __restrict__ dtw, const float* __restrict__ dtb,
    const float* __restrict__ A_log,
    float* __restrict__ sega, float* __restrict__ segh) {
  __shared__ float sx[SEGLEN * XSTR];
  int s = blockIdx.x, b = blockIdx.y, d = threadIdx.x;
  size_t rbase = ((size_t)b * LL + (size_t)s * SEGLEN) * 64;
  load_sx(sx, xdbl, rbase, d);
  __syncthreads();
  if (a_is_integer(A_log, d))
    scan1_body<true>(s, b, d, sx, u_pk, dtw, dtb, A_log, sega, segh);
  else
    scan1_body<false>(s, b, d, sx, u_pk, dtw, dtb, A_log, sega, segh);
}

__global__ __launch_bounds__(256) void scan_combine(float* __restrict__ sega,
    const float* __restrict__ segh) {
  int g = blockIdx.x * 256 + threadIdx.x;
  size_t off = (size_t)(g >> 2) * 16 + (g & 3) * 4;
  float4 h0 = make_float4(0.f, 0.f, 0.f, 0.f);
  for (int s = 0; s < NSEG; s++) {
    size_t q = (size_t)s * 65536 + off;
    float4 a = *(float4*)(sega + q);
    float4 hh = *(float4*)(segh + q);
    *(float4*)(sega + q) = h0;
    h0.x = a.x * h0.x + hh.x;
    h0.y = a.y * h0.y + hh.y;
    h0.z = a.z * h0.z + hh.z;
    h0.w = a.w * h0.w + hh.w;
  }
}

// ---------------------------------------------------------------------------
// FUSED scan_phase2 + out_proj + residual + RMSNorm (NSEG=64, 32-row tile).
// Burst-prefetched u/zs loads (8 steps ahead).
// ---------------------------------------------------------------------------
template<bool FAST>
__device__ inline void scan2_to_lds(int s, int b, int d, const float* sx,
    const uint* __restrict__ u_pk, const uint* __restrict__ zs_pk,
    const float* __restrict__ dtw, const float* __restrict__ dtb,
    const float* __restrict__ A_log, const float* __restrict__ Dp,
    const float* __restrict__ sega, uint* __restrict__ ybuf) {
  float wdt[8];
#pragma unroll
  for (int j = 0; j < 8; j++) wdt[j] = dtw[d * 8 + j];
  float bdt = dtb[d];
  float h[DS];
  size_t o = ((size_t)s * 4096 + b * 256 + d) * DS;
#pragma unroll
  for (int n = 0; n < DS; n++) h[n] = sega[o + n];
  float Dd = Dp[d];
  size_t base = (size_t)b * LL + (size_t)s * SEGLEN;
  const uint* up = u_pk + base * DI + d;
  const uint* zp = zs_pk + base * DI + d;
  for (int t0 = 0; t0 < SEGLEN; t0 += 8) {
    uint ub[8], zb[8];
#pragma unroll
    for (int q = 0; q < 8; q++) {
      ub[q] = up[(size_t)q * DI];
      zb[q] = zp[(size_t)q * DI];
    }
    up += 8 * DI; zp += 8 * DI;
#pragma unroll
    for (int q = 0; q < 8; q++) {
      int t = t0 + q;
      const float* xr = sx + t * XSTR;
      float dt = bdt;
#pragma unroll
      for (int j = 0; j < 8; j++) dt += xr[j] * wdt[j];
      float dl = softplus_f(dt);
      float u = unpack_hl(ub[q]);
      float du = dl * u;
      float acc = 0.f;
      if (FAST) {
        float rp[DS];
        make_powers(__expf(-dl), rp);
#pragma unroll
        for (int n = 0; n < DS; n++) {
          h[n] = fmaf(rp[n], h[n], du * xr[8 + n]);
          acc = fmaf(h[n], xr[24 + n], acc);
        }
      } else {
#pragma unroll
        for (int n = 0; n < DS; n++) {
          float dA = __expf(dl * (-__expf(A_log[d * DS + n])));
          h[n] = fmaf(dA, h[n], du * xr[8 + n]);
          acc = fmaf(h[n], xr[24 + n], acc);
        }
      }
      float zs = unpack_hl(zb[q]);
      float yv = (acc + u * Dd) * zs;
      ybuf[t * YSTR + d] = pack_hl(yv);
    }
  }
}

__global__ __launch_bounds__(256, 4) void scan2_outproj(
    const uint* __restrict__ u_pk, const uint* __restrict__ zs_pk,
    const float* __restrict__ xdbl, const float* __restrict__ dtw,
    const float* __restrict__ dtb, const float* __restrict__ A_log,
    const float* __restrict__ Dp, const float* __restrict__ sega,
    const bf16* __restrict__ Wh, const bf16* __restrict__ Wl,
    float* __restrict__ hbuf, const float* __restrict__ nw,
    float* __restrict__ of, bf16* __restrict__ oh, bf16* __restrict__ ol) {
  __shared__ float sx[SEGLEN * XSTR];      // 5 KB
  __shared__ uint ybuf[32 * YSTR];         // 34.3 KB (packed y; later fp32 tile)
  int s = blockIdx.x, b = blockIdx.y;
  int tid = threadIdx.x, d = tid;
  size_t rbase = ((size_t)b * LL + (size_t)s * SEGLEN) * 64;
  load_sx(sx, xdbl, rbase, tid);
  __syncthreads();
  if (a_is_integer(A_log, d))
    scan2_to_lds<true>(s, b, d, sx, u_pk, zs_pk, dtw, dtb, A_log, Dp, sega, ybuf);
  else
    scan2_to_lds<false>(s, b, d, sx, u_pk, zs_pk, dtw, dtb, A_log, Dp, sega, ybuf);
  __syncthreads();
  // out_proj: C[32x128] = y[32x256] @ Wop[128x256]^T, wave covers 32 cols
  int wave = tid >> 6, lane = tid & 63;
  int r16 = lane & 15, quad = lane >> 4;
  int n0 = wave * 32;
  size_t brow[2];
#pragma unroll
  for (int j = 0; j < 2; j++)
    brow[j] = (size_t)(n0 + j * 16 + r16) * DI + quad * 8;
  f32x4 acc[2][2] = {};
#pragma unroll
  for (int kk = 0; kk < 8; kk++) {
    int k0 = quad * 8 + kk * 32;
    bf16x8 ah[2], al[2], bh[2], bl[2];
#pragma unroll
    for (int i = 0; i < 2; i++) {
      ux8 yw = *(const ux8*)(ybuf + (i * 16 + r16) * YSTR + k0);
#pragma unroll
      for (int e = 0; e < 8; e++) {
        ah[i][e] = (short)(yw[e] & 0xffffu);
        al[i][e] = (short)(yw[e] >> 16);
      }
    }
#pragma unroll
    for (int j = 0; j < 2; j++) {
      bh[j] = *(const bf16x8*)(Wh + brow[j] + kk * 32);
      bl[j] = *(const bf16x8*)(Wl + brow[j] + kk * 32);
    }
#pragma unroll
    for (int i = 0; i < 2; i++)
#pragma unroll
      for (int j = 0; j < 2; j++) {
        acc[i][j] = __builtin_amdgcn_mfma_f32_16x16x32_bf16(ah[i], bh[j], acc[i][j], 0, 0, 0);
        acc[i][j] = __builtin_amdgcn_mfma_f32_16x16x32_bf16(ah[i], bl[j], acc[i][j], 0, 0, 0);
        acc[i][j] = __builtin_amdgcn_mfma_f32_16x16x32_bf16(al[i], bh[j], acc[i][j], 0, 0, 0);
      }
  }
  __syncthreads();   // all LDS y reads done; reuse ybuf as fp32 tile 32x132
  float* tile = (float*)ybuf;
#pragma unroll
  for (int i = 0; i < 2; i++)
#pragma unroll
    for (int j = 0; j < 2; j++)
#pragma unroll
      for (int r = 0; r < 4; r++) {
        int rl = i * 16 + quad * 4 + r;
        int col = n0 + j * 16 + r16;
        tile[rl * 132 + col] = acc[i][j][r];
      }
  __syncthreads();
  // epilogue: residual + rmsnorm + bf16 split, coalesced
  size_t mbase = (size_t)b * LL + (size_t)s * SEGLEN;
#pragma unroll
  for (int it = 0; it < 4; it++) {
    int idx = it * 256 + tid;
    int row = idx >> 5, c4 = idx & 31;
    size_t g = (mbase + row) * DM + c4 * 4;
    float4 hv = *(float4*)(hbuf + g);
    const float* tp = tile + row * 132 + c4 * 4;
    float4 v = make_float4(tp[0] + hv.x, tp[1] + hv.y, tp[2] + hv.z, tp[3] + hv.w);
    *(float4*)(hbuf + g) = v;
    float ss = v.x * v.x + v.y * v.y + v.z * v.z + v.w * v.w;
    ss += __shfl_xor(ss, 1);
    ss += __shfl_xor(ss, 2);
    ss += __shfl_xor(ss, 4);
    ss += __shfl_xor(ss, 8);
    ss += __shfl_xor(ss, 16);
    float sc = rsqrtf(ss * (1.f / DM) + 1e-5f);
    float4 w4 = *(const float4*)(nw + c4 * 4);
    float n0v = v.x * sc * w4.x, n1v = v.y * sc * w4.y;
    float n2v = v.z * sc * w4.z, n3v = v.w * sc * w4.w;
    if (of) *(float4*)(of + g) = make_float4(n0v, n1v, n2v, n3v);
    short h0s, l0s, h1s, l1s, h2s, l2s, h3s, l3s;
    split_bits2(n0v, h0s, l0s); split_bits2(n1v, h1s, l1s);
    split_bits2(n2v, h2s, l2s); split_bits2(n3v, h3s, l3s);
    bf16x4s hb, lb;
    hb[0] = h0s; hb[1] = h1s; hb[2] = h2s; hb[3] = h3s;
    lb[0] = l0s; lb[1] = l1s; lb[2] = l2s; lb[3] = l3s;
    *(bf16x4s*)(oh + g) = hb;
    *(bf16x4s*)(ol + g) = lb;
  }
}

// ---------------------------------------------------------------------------
// Pooling (deterministic) + classifier
// ---------------------------------------------------------------------------
__global__ __launch_bounds__(256) void pool_partial(const float* __restrict__ fn,
    float* __restrict__ partial) {
  __shared__ float red[256];
  int b = blockIdx.x, c = blockIdx.y;
  int tid = threadIdx.x;
  int d = tid & 127, rp_ = tid >> 7;
  float s = 0.f;
  size_t base = (size_t)b * LL + c * 256;
  for (int i = 0; i < 128; i++) {
    int row = i * 2 + rp_;
    s += fn[(base + row) * DM + d];
  }
  red[tid] = s;
  __syncthreads();
  if (tid < 128) partial[((size_t)b * 8 + c) * 128 + tid] = red[tid] + red[tid + 128];
}

__global__ void pool_reduce(const float* __restrict__ partial,
    float* __restrict__ pooled) {
  int idx = blockIdx.x * 256 + threadIdx.x;   // 2048
  int b = idx >> 7, d = idx & 127;
  float s = 0.f;
#pragma unroll
  for (int c = 0; c < 8; c++) s += partial[((size_t)b * 8 + c) * 128 + d];
  pooled[idx] = s * (1.f / LL);
}

__global__ void cls_kernel(const float* __restrict__ pooled,
    const float* __restrict__ cw, const float* __restrict__ cb,
    float* __restrict__ out) {
  int t = threadIdx.x;
  if (t < 80) {
    int b = t / 5, c = t % 5;
    float acc = cb[c];
    for (int d = 0; d < DM; d++) acc += pooled[b * DM + d] * cw[c * DM + d];
    out[t] = acc;
  }
}

// ---------------------------------------------------------------------------
extern "C" void kernel_launch(void* const* d_in, const int* in_sizes, int n_in,
                              void* d_out, int out_size, void* d_ws, size_t ws_size,
                              hipStream_t stream) {
  const float* x         = (const float*)d_in[0];
  const float* enc_w     = (const float*)d_in[1];
  const float* enc_b     = (const float*)d_in[2];
  const float* norm_w    = (const float*)d_in[3];
  const float* in_proj_w = (const float*)d_in[4];
  const float* conv_w    = (const float*)d_in[5];
  const float* conv_b    = (const float*)d_in[6];
  const float* x_proj_w  = (const float*)d_in[7];
  const float* dt_proj_w = (const float*)d_in[8];
  const float* dt_proj_b = (const float*)d_in[9];
  const float* A_log     = (const float*)d_in[10];
  const float* Dp        = (const float*)d_in[11];
  const float* out_proj_w= (const float*)d_in[12];
  const float* norm_f_w  = (const float*)d_in[13];
  const float* cls_w     = (const float*)d_in[14];
  const float* cls_b     = (const float*)d_in[15];
  float* out = (float*)d_out;

  float* ws = (float*)d_ws;
  float* h       = ws;                       // 4,194,304
  float* xdbl    = ws + 4194304;             // 2,097,152
  float* sega    = ws + 6291456;             // 4,194,304
  float* segh    = ws + 10485760;            // 4,194,304
  uint*  zs_pk   = (uint*)(ws + 14680064);   // 8,388,608
  uint*  u_pk    = (uint*)(ws + 23068672);   // 8,388,608
  uint*  xm_pk   = (uint*)(ws + 31457280);   // 8,388,608
  float* partial = ws + 39845888;            // 16,384
  float* pooled  = ws + 39862272;            // 2,048
  bf16* u0     = (bf16*)(ws + 39864320);
  bf16* xn_hi  = u0;                         // MP*128
  bf16* xn_lo  = u0 + 4194304;
  bf16* wip_hi = u0 + 8388608;               // 262,144
  bf16* wip_lo = wip_hi + 262144;
  bf16* wxp_hi = wip_lo + 262144;            // 65,536 (padded)
  bf16* wxp_lo = wxp_hi + 65536;
  bf16* wop_hi = wxp_lo + 65536;             // 131,072
  bf16* wop_lo = wop_hi + 131072;
  float* fnorm = (float*)xm_pk;              // xm dead after layer-3 gemm_conv

  split_w<<<1024, 256, 0, stream>>>(in_proj_w, wip_hi, wip_lo, 262144);
  split_w_pad<<<256, 256, 0, stream>>>(x_proj_w, wxp_hi, wxp_lo);
  split_w<<<512, 256, 0, stream>>>(out_proj_w, wop_hi, wop_lo, 131072);

  encoder_kernel<<<MP * DM / 256, 256, 0, stream>>>(x, enc_w, enc_b, h);
  rmsnorm_kernel<<<MP / 4, 256, 0, stream>>>(h, norm_w, xn_hi, xn_lo);

  for (int i = 0; i < 4; i++) {
    gemm_inproj<<<MP / 16, 256, 0, stream>>>(xn_hi, xn_lo,
        wip_hi + i * 65536, wip_lo + i * 65536, xm_pk, zs_pk);
    gemm_conv<<<MP / 64, 256, 0, stream>>>(xm_pk,
        wxp_hi + i * 16384, wxp_lo + i * 16384,
        conv_w + i * DI * 4, conv_b + i * DI, xdbl, u_pk);
    scan_phase1<<<dim3(NSEG, BB), 256, 0, stream>>>(u_pk, xdbl,
        dt_proj_w + i * 2048, dt_proj_b + i * DI, A_log + i * DI * DS, sega, segh);
    scan_combine<<<64, 256, 0, stream>>>(sega, segh);
    scan2_outproj<<<dim3(NSEG, BB), 256, 0, stream>>>(u_pk, zs_pk, xdbl,
        dt_proj_w + i * 2048, dt_proj_b + i * DI, A_log + i * DI * DS,
        Dp + i * DI, sega, wop_hi + i * 32768, wop_lo + i * 32768, h,
        (i < 3) ? norm_w + (i + 1) * DM : norm_f_w,
        (i < 3) ? nullptr : fnorm, xn_hi, xn_lo);
  }

  pool_partial<<<dim3(BB, 8), 256, 0, stream>>>(fnorm, partial);
  pool_reduce<<<8, 256, 0, stream>>>(partial, pooled);
  cls_kernel<<<1, 128, 0, stream>>>(pooled, cls_w, cls_b, out);
}

// Round 19
// 799.991 us; speedup vs baseline: 1.3294x; 1.3294x over previous
//
#include <hip/hip_runtime.h>
#include <hip/hip_bf16.h>
#include <cstddef>

#define BB 16
#define LL 2048
#define DM 128
#define DI 256
#define DS 16
#define MP (BB*LL)          // 32768 positions
#define NSEG 64
#define SEGLEN (LL/NSEG)    // 32
#define YSTR 268            // ybuf LDS row stride (dwords)
#define XSTR 40             // sx LDS row stride (floats)

typedef __attribute__((ext_vector_type(8))) short bf16x8;
typedef __attribute__((ext_vector_type(4))) short bf16x4s;
typedef __attribute__((ext_vector_type(8))) unsigned int ux8;
typedef __attribute__((ext_vector_type(4))) float f32x4;
typedef __hip_bfloat16 bf16;
typedef unsigned int uint;

__device__ inline void bf16split(float x, bf16& h, bf16& l) {
  h = __float2bfloat16(x);
  l = __float2bfloat16(x - __bfloat162float(h));
}
__device__ inline float bf2f(bf16 v) { return __bfloat162float(v); }
__device__ inline void split_bits2(float x, short& hs, short& ls) {
  bf16 hb = __float2bfloat16(x);
  bf16 lb = __float2bfloat16(x - __bfloat162float(hb));
  hs = *(short*)&hb;
  ls = *(short*)&lb;
}
__device__ inline float sigm(float x) {
  return __builtin_amdgcn_rcpf(1.f + __expf(-x));
}
__device__ inline uint pk2(short h, short l) {
  return (uint)(unsigned short)h | ((uint)(unsigned short)l << 16);
}
__device__ inline uint pack_hl(float x) {
  short hs, ls; split_bits2(x, hs, ls);
  return pk2(hs, ls);
}
__device__ inline float unpack_hl(uint w) {
  return __uint_as_float(w << 16) + __uint_as_float(w & 0xffff0000u);
}

// ---------------------------------------------------------------------------
// in_proj: block = 32 positions x 256 cols. Packed dword outputs, no LDS.
// ---------------------------------------------------------------------------
__global__ __launch_bounds__(256, 4) void gemm_inproj(
    const bf16* __restrict__ Ah, const bf16* __restrict__ Al,
    const bf16* __restrict__ Wh, const bf16* __restrict__ Wl,
    uint* __restrict__ xm_pk, uint* __restrict__ zs_pk) {
  int tid = threadIdx.x;
  int wave = tid >> 6, lane = tid & 63;
  int r16 = lane & 15, quad = lane >> 4;
  int bid = blockIdx.x;
  int nh = bid & 1, mb = bid >> 1;
  int m0 = mb * 32;
  int n0 = nh * 256 + wave * 64;
  size_t arow[2], brow[4];
#pragma unroll
  for (int i = 0; i < 2; i++)
    arow[i] = (size_t)(m0 + i * 16 + r16) * DM + quad * 8;
#pragma unroll
  for (int j = 0; j < 4; j++)
    brow[j] = (size_t)(n0 + j * 16 + r16) * DM + quad * 8;
  f32x4 acc[2][4] = {};
#pragma unroll
  for (int kk = 0; kk < 4; kk++) {
    int ko = kk * 32;
    bf16x8 ah[2], al[2], bh[4], bl[4];
#pragma unroll
    for (int i = 0; i < 2; i++) {
      ah[i] = *(const bf16x8*)(Ah + arow[i] + ko);
      al[i] = *(const bf16x8*)(Al + arow[i] + ko);
    }
#pragma unroll
    for (int j = 0; j < 4; j++) {
      bh[j] = *(const bf16x8*)(Wh + brow[j] + ko);
      bl[j] = *(const bf16x8*)(Wl + brow[j] + ko);
    }
#pragma unroll
    for (int i = 0; i < 2; i++)
#pragma unroll
      for (int j = 0; j < 4; j++) {
        acc[i][j] = __builtin_amdgcn_mfma_f32_16x16x32_bf16(ah[i], bh[j], acc[i][j], 0, 0, 0);
        acc[i][j] = __builtin_amdgcn_mfma_f32_16x16x32_bf16(ah[i], bl[j], acc[i][j], 0, 0, 0);
        acc[i][j] = __builtin_amdgcn_mfma_f32_16x16x32_bf16(al[i], bh[j], acc[i][j], 0, 0, 0);
      }
  }
  bool isz = (n0 >= 256);
  uint* dst = isz ? zs_pk : xm_pk;
  int cb = n0 & 255;
#pragma unroll
  for (int i = 0; i < 2; i++)
#pragma unroll
    for (int j = 0; j < 4; j++)
#pragma unroll
      for (int r = 0; r < 4; r++) {
        int row = m0 + i * 16 + quad * 4 + r;
        int col = cb + j * 16 + r16;
        float v = acc[i][j][r];
        if (isz) v *= sigm(v);
        dst[(size_t)row * DI + col] = pack_hl(v);
      }
}

// ---------------------------------------------------------------------------
// x_proj with fused conv+SiLU. Wave owns a distinct 16-row m-tile x 48 cols.
// ---------------------------------------------------------------------------
__global__ __launch_bounds__(256, 2) void gemm_conv(
    const uint* __restrict__ xm_pk,
    const bf16* __restrict__ Wh, const bf16* __restrict__ Wl,
    const float* __restrict__ cw, const float* __restrict__ cb,
    float* __restrict__ C, uint* __restrict__ u_pk) {
  __shared__ float scw[DI * 4 + DI];
  int tid = threadIdx.x;
  {
    float4 w4 = *(const float4*)(cw + tid * 4);
    *(float4*)(scw + tid * 4) = w4;
    scw[DI * 4 + tid] = cb[tid];
  }
  __syncthreads();
  int wave = tid >> 6, lane = tid & 63;
  int r16 = lane & 15, quad = lane >> 4;
  int m0 = blockIdx.x * 64 + wave * 16;
  int m = m0 + r16;
  int l = m & (LL - 1);
  size_t rb[4]; float msk[3];
#pragma unroll
  for (int t = 0; t < 3; t++) {
    msk[t] = (l >= (3 - t)) ? 1.f : 0.f;
    int mr = m - 3 + t; if (mr < 0) mr = 0;
    rb[t] = (size_t)mr * DI;
  }
  rb[3] = (size_t)m * DI;
  size_t brow[3];
#pragma unroll
  for (int j = 0; j < 3; j++)
    brow[j] = (size_t)(j * 16 + r16) * DI + quad * 8;
  f32x4 acc[3] = {};
#pragma unroll
  for (int kk = 0; kk < 8; kk++) {
    int ko = quad * 8 + kk * 32;
    bf16x8 ah, al, bh[3], bl[3];
    ux8 xv[4];
#pragma unroll
    for (int t = 0; t < 4; t++)
      xv[t] = *(const ux8*)(xm_pk + rb[t] + ko);
#pragma unroll
    for (int e = 0; e < 8; e++) {
      int k = ko + e;
      float x0 = unpack_hl(xv[0][e]) * msk[0];
      float x1 = unpack_hl(xv[1][e]) * msk[1];
      float x2 = unpack_hl(xv[2][e]) * msk[2];
      float x3 = unpack_hl(xv[3][e]);
      float c0 = scw[DI * 4 + k] + scw[k*4]*x0 + scw[k*4+1]*x1 + scw[k*4+2]*x2 + scw[k*4+3]*x3;
      float u = c0 * sigm(c0);
      short hs, ls; split_bits2(u, hs, ls);
      ah[e] = hs; al[e] = ls;
    }
    {
      size_t g = rb[3] + ko;
      uint4 p0, p1;
      p0.x = pk2(ah[0], al[0]); p0.y = pk2(ah[1], al[1]);
      p0.z = pk2(ah[2], al[2]); p0.w = pk2(ah[3], al[3]);
      p1.x = pk2(ah[4], al[4]); p1.y = pk2(ah[5], al[5]);
      p1.z = pk2(ah[6], al[6]); p1.w = pk2(ah[7], al[7]);
      *(uint4*)(u_pk + g) = p0;
      *(uint4*)(u_pk + g + 4) = p1;
    }
#pragma unroll
    for (int j = 0; j < 3; j++) {
      bh[j] = *(const bf16x8*)(Wh + brow[j] + kk * 32);
      bl[j] = *(const bf16x8*)(Wl + brow[j] + kk * 32);
    }
#pragma unroll
    for (int j = 0; j < 3; j++) {
      acc[j] = __builtin_amdgcn_mfma_f32_16x16x32_bf16(ah, bh[j], acc[j], 0, 0, 0);
      acc[j] = __builtin_amdgcn_mfma_f32_16x16x32_bf16(ah, bl[j], acc[j], 0, 0, 0);
      acc[j] = __builtin_amdgcn_mfma_f32_16x16x32_bf16(al, bh[j], acc[j], 0, 0, 0);
    }
  }
#pragma unroll
  for (int j = 0; j < 3; j++)
#pragma unroll
    for (int r = 0; r < 4; r++) {
      int row = m0 + quad * 4 + r;
      int col = j * 16 + r16;
      C[(size_t)row * 64 + col] = acc[j][r];
    }
}

// ---------------------------------------------------------------------------
// Encoder (K=12, direct)
// ---------------------------------------------------------------------------
__global__ __launch_bounds__(256) void encoder_kernel(const float* __restrict__ x,
    const float* __restrict__ ew, const float* __restrict__ eb,
    float* __restrict__ h) {
  int idx = blockIdx.x * 256 + threadIdx.x;
  int d = idx & 127, m = idx >> 7;
  float acc = eb[d];
#pragma unroll
  for (int c = 0; c < 12; c++) acc += x[m * 12 + c] * ew[d * 12 + c];
  h[idx] = acc;
}

// ---------------------------------------------------------------------------
// Weight splits
// ---------------------------------------------------------------------------
__global__ void split_w(const float* __restrict__ src, bf16* __restrict__ hi,
                        bf16* __restrict__ lo, int n) {
  int i = blockIdx.x * 256 + threadIdx.x;
  if (i < n) bf16split(src[i], hi[i], lo[i]);
}

__global__ void split_w_pad(const float* __restrict__ src, bf16* __restrict__ hi,
                            bf16* __restrict__ lo) {
  int i = blockIdx.x * 256 + threadIdx.x;   // < 4*64*256
  int l = i >> 14, rem = i & 16383, r = rem >> 8, k = rem & 255;
  float v = (r < 40) ? src[l * 10240 + r * 256 + k] : 0.f;
  bf16split(v, hi[i], lo[i]);
}

// ---------------------------------------------------------------------------
// RMSNorm (layer-0 input only)
// ---------------------------------------------------------------------------
__global__ __launch_bounds__(256) void rmsnorm_kernel(const float* __restrict__ x,
    const float* __restrict__ w, bf16* __restrict__ oh, bf16* __restrict__ ol) {
  int lane = threadIdx.x & 63;
  int pos = blockIdx.x * 4 + (threadIdx.x >> 6);
  const float* row = x + (size_t)pos * DM;
  float v0 = row[lane], v1 = row[lane + 64];
  float ss = v0 * v0 + v1 * v1;
#pragma unroll
  for (int off = 1; off < 64; off <<= 1) ss += __shfl_xor(ss, off);
  float sc = rsqrtf(ss * (1.f / DM) + 1e-5f);
  float a = v0 * sc * w[lane], b = v1 * sc * w[lane + 64];
  size_t o = (size_t)pos * DM;
  bf16split(a, oh[o + lane], ol[o + lane]);
  bf16split(b, oh[o + lane + 64], ol[o + lane + 64]);
}

// ---------------------------------------------------------------------------
// Scan helpers
// ---------------------------------------------------------------------------
__device__ inline float softplus_f(float a) {
  float r = __logf(1.f + __expf(a));
  return a > 15.f ? a : r;
}

__device__ inline void make_powers(float r, float* rp) {
  rp[0] = r;
#pragma unroll
  for (int n = 1; n < 16; n++) {
    int a = (n + 1) >> 1, b = (n + 1) - a;
    rp[n] = rp[a - 1] * rp[b - 1];
  }
}

__device__ inline bool a_is_integer(const float* A_log, int d) {
  bool ok = true;
#pragma unroll
  for (int n = 0; n < DS; n++) {
    float Ad = -__expf(A_log[d * DS + n]);
    ok = ok && (fabsf(Ad + (float)(n + 1)) < 1e-3f);
  }
  return ok;
}

// load 32 rows x 40 cols of xdbl (cols 0..39) into LDS, stride XSTR
__device__ inline void load_sx(float* sx, const float* xdbl, size_t rbase, int tid) {
#pragma unroll
  for (int j = 0; j < 2; j++) {
    int idx = j * 256 + tid;       // < 320 = 32 rows x 10 float4
    if (idx < 320) {
      int row = idx / 10, c = idx % 10;
      *(float4*)(sx + row * XSTR + c * 4) = *(const float4*)(xdbl + rbase + row * 64 + c * 4);
    }
  }
}

template<bool FAST>
__device__ inline void scan1_body(int s, int b, int d, const float* sx,
    const uint* __restrict__ u_pk,
    const float* __restrict__ dtw, const float* __restrict__ dtb,
    const float* __restrict__ A_log,
    float* __restrict__ sega, float* __restrict__ segh) {
  float wdt[8];
#pragma unroll
  for (int j = 0; j < 8; j++) wdt[j] = dtw[d * 8 + j];
  float bdt = dtb[d];
  float h[DS];
#pragma unroll
  for (int n = 0; n < DS; n++) h[n] = 0.f;
  float R = 1.f;
  float ap[DS];
  if (!FAST) {
#pragma unroll
    for (int n = 0; n < DS; n++) ap[n] = 1.f;
  }
  size_t base = (size_t)b * LL + (size_t)s * SEGLEN;
  const uint* up = u_pk + base * DI + d;
  // 1-deep rolling scalar prefetch (2 live regs; boundary read stays in d_ws)
  uint ub = *up;
#pragma unroll 4
  for (int t = 0; t < SEGLEN; t++) {
    up += DI;
    uint ub_next = *up;
    const float* xr = sx + t * XSTR;
    float dt = bdt;
#pragma unroll
    for (int j = 0; j < 8; j++) dt += xr[j] * wdt[j];
    float dl = softplus_f(dt);
    float u = unpack_hl(ub);
    float du = dl * u;
    if (FAST) {
      float rp[DS];
      make_powers(__expf(-dl), rp);
      R *= rp[0];
#pragma unroll
      for (int n = 0; n < DS; n++) h[n] = fmaf(rp[n], h[n], du * xr[8 + n]);
    } else {
#pragma unroll
      for (int n = 0; n < DS; n++) {
        float dA = __expf(dl * (-__expf(A_log[d * DS + n])));
        h[n] = fmaf(dA, h[n], du * xr[8 + n]);
        ap[n] *= dA;
      }
    }
    ub = ub_next;
  }
  if (FAST) make_powers(R, ap);
  size_t o = ((size_t)s * 4096 + b * 256 + d) * DS;
#pragma unroll
  for (int j = 0; j < 4; j++) {
    *(float4*)(sega + o + 4 * j) = make_float4(ap[4*j], ap[4*j+1], ap[4*j+2], ap[4*j+3]);
    *(float4*)(segh + o + 4 * j) = make_float4(h[4*j], h[4*j+1], h[4*j+2], h[4*j+3]);
  }
}

__global__ __launch_bounds__(256, 4) void scan_phase1(
    const uint* __restrict__ u_pk, const float* __restrict__ xdbl,
    const float* __restrict__ dtw, const float* __restrict__ dtb,
    const float* __restrict__ A_log,
    float* __restrict__ sega, float* __restrict__ segh) {
  __shared__ float sx[SEGLEN * XSTR];
  int s = blockIdx.x, b = blockIdx.y, d = threadIdx.x;
  size_t rbase = ((size_t)b * LL + (size_t)s * SEGLEN) * 64;
  load_sx(sx, xdbl, rbase, d);
  __syncthreads();
  if (a_is_integer(A_log, d))
    scan1_body<true>(s, b, d, sx, u_pk, dtw, dtb, A_log, sega, segh);
  else
    scan1_body<false>(s, b, d, sx, u_pk, dtw, dtb, A_log, sega, segh);
}

__global__ __launch_bounds__(256) void scan_combine(float* __restrict__ sega,
    const float* __restrict__ segh) {
  int g = blockIdx.x * 256 + threadIdx.x;
  size_t off = (size_t)(g >> 2) * 16 + (g & 3) * 4;
  float4 h0 = make_float4(0.f, 0.f, 0.f, 0.f);
  for (int s = 0; s < NSEG; s++) {
    size_t q = (size_t)s * 65536 + off;
    float4 a = *(float4*)(sega + q);
    float4 hh = *(float4*)(segh + q);
    *(float4*)(sega + q) = h0;
    h0.x = a.x * h0.x + hh.x;
    h0.y = a.y * h0.y + hh.y;
    h0.z = a.z * h0.z + hh.z;
    h0.w = a.w * h0.w + hh.w;
  }
}

// ---------------------------------------------------------------------------
// FUSED scan_phase2 + out_proj + residual + RMSNorm (NSEG=64, 32-row tile).
// 1-deep rolling scalar prefetch on u/zs.
// ---------------------------------------------------------------------------
template<bool FAST>
__device__ inline void scan2_to_lds(int s, int b, int d, const float* sx,
    const uint* __restrict__ u_pk, const uint* __restrict__ zs_pk,
    const float* __restrict__ dtw, const float* __restrict__ dtb,
    const float* __restrict__ A_log, const float* __restrict__ Dp,
    const float* __restrict__ sega, uint* __restrict__ ybuf) {
  float wdt[8];
#pragma unroll
  for (int j = 0; j < 8; j++) wdt[j] = dtw[d * 8 + j];
  float bdt = dtb[d];
  float h[DS];
  size_t o = ((size_t)s * 4096 + b * 256 + d) * DS;
#pragma unroll
  for (int n = 0; n < DS; n++) h[n] = sega[o + n];
  float Dd = Dp[d];
  size_t base = (size_t)b * LL + (size_t)s * SEGLEN;
  const uint* up = u_pk + base * DI + d;
  const uint* zp = zs_pk + base * DI + d;
  uint ub = *up, zb = *zp;
#pragma unroll 4
  for (int t = 0; t < SEGLEN; t++) {
    up += DI; zp += DI;
    uint ub_next = *up;
    uint zb_next = *zp;
    const float* xr = sx + t * XSTR;
    float dt = bdt;
#pragma unroll
    for (int j = 0; j < 8; j++) dt += xr[j] * wdt[j];
    float dl = softplus_f(dt);
    float u = unpack_hl(ub);
    float du = dl * u;
    float acc = 0.f;
    if (FAST) {
      float rp[DS];
      make_powers(__expf(-dl), rp);
#pragma unroll
      for (int n = 0; n < DS; n++) {
        h[n] = fmaf(rp[n], h[n], du * xr[8 + n]);
        acc = fmaf(h[n], xr[24 + n], acc);
      }
    } else {
#pragma unroll
      for (int n = 0; n < DS; n++) {
        float dA = __expf(dl * (-__expf(A_log[d * DS + n])));
        h[n] = fmaf(dA, h[n], du * xr[8 + n]);
        acc = fmaf(h[n], xr[24 + n], acc);
      }
    }
    float zs = unpack_hl(zb);
    float yv = (acc + u * Dd) * zs;
    ybuf[t * YSTR + d] = pack_hl(yv);
    ub = ub_next; zb = zb_next;
  }
}

__global__ __launch_bounds__(256, 4) void scan2_outproj(
    const uint* __restrict__ u_pk, const uint* __restrict__ zs_pk,
    const float* __restrict__ xdbl, const float* __restrict__ dtw,
    const float* __restrict__ dtb, const float* __restrict__ A_log,
    const float* __restrict__ Dp, const float* __restrict__ sega,
    const bf16* __restrict__ Wh, const bf16* __restrict__ Wl,
    float* __restrict__ hbuf, const float* __restrict__ nw,
    float* __restrict__ of, bf16* __restrict__ oh, bf16* __restrict__ ol) {
  __shared__ float sx[SEGLEN * XSTR];      // 5 KB
  __shared__ uint ybuf[32 * YSTR];         // 34.3 KB (packed y; later fp32 tile)
  int s = blockIdx.x, b = blockIdx.y;
  int tid = threadIdx.x, d = tid;
  size_t rbase = ((size_t)b * LL + (size_t)s * SEGLEN) * 64;
  load_sx(sx, xdbl, rbase, tid);
  __syncthreads();
  if (a_is_integer(A_log, d))
    scan2_to_lds<true>(s, b, d, sx, u_pk, zs_pk, dtw, dtb, A_log, Dp, sega, ybuf);
  else
    scan2_to_lds<false>(s, b, d, sx, u_pk, zs_pk, dtw, dtb, A_log, Dp, sega, ybuf);
  __syncthreads();
  // out_proj: C[32x128] = y[32x256] @ Wop[128x256]^T, wave covers 32 cols
  int wave = tid >> 6, lane = tid & 63;
  int r16 = lane & 15, quad = lane >> 4;
  int n0 = wave * 32;
  size_t brow[2];
#pragma unroll
  for (int j = 0; j < 2; j++)
    brow[j] = (size_t)(n0 + j * 16 + r16) * DI + quad * 8;
  f32x4 acc[2][2] = {};
#pragma unroll
  for (int kk = 0; kk < 8; kk++) {
    int k0 = quad * 8 + kk * 32;
    bf16x8 ah[2], al[2], bh[2], bl[2];
#pragma unroll
    for (int i = 0; i < 2; i++) {
      ux8 yw = *(const ux8*)(ybuf + (i * 16 + r16) * YSTR + k0);
#pragma unroll
      for (int e = 0; e < 8; e++) {
        ah[i][e] = (short)(yw[e] & 0xffffu);
        al[i][e] = (short)(yw[e] >> 16);
      }
    }
#pragma unroll
    for (int j = 0; j < 2; j++) {
      bh[j] = *(const bf16x8*)(Wh + brow[j] + kk * 32);
      bl[j] = *(const bf16x8*)(Wl + brow[j] + kk * 32);
    }
#pragma unroll
    for (int i = 0; i < 2; i++)
#pragma unroll
      for (int j = 0; j < 2; j++) {
        acc[i][j] = __builtin_amdgcn_mfma_f32_16x16x32_bf16(ah[i], bh[j], acc[i][j], 0, 0, 0);
        acc[i][j] = __builtin_amdgcn_mfma_f32_16x16x32_bf16(ah[i], bl[j], acc[i][j], 0, 0, 0);
        acc[i][j] = __builtin_amdgcn_mfma_f32_16x16x32_bf16(al[i], bh[j], acc[i][j], 0, 0, 0);
      }
  }
  __syncthreads();   // all LDS y reads done; reuse ybuf as fp32 tile 32x132
  float* tile = (float*)ybuf;
#pragma unroll
  for (int i = 0; i < 2; i++)
#pragma unroll
    for (int j = 0; j < 2; j++)
#pragma unroll
      for (int r = 0; r < 4; r++) {
        int rl = i * 16 + quad * 4 + r;
        int col = n0 + j * 16 + r16;
        tile[rl * 132 + col] = acc[i][j][r];
      }
  __syncthreads();
  // epilogue: residual + rmsnorm + bf16 split, coalesced
  size_t mbase = (size_t)b * LL + (size_t)s * SEGLEN;
#pragma unroll
  for (int it = 0; it < 4; it++) {
    int idx = it * 256 + tid;
    int row = idx >> 5, c4 = idx & 31;
    size_t g = (mbase + row) * DM + c4 * 4;
    float4 hv = *(float4*)(hbuf + g);
    const float* tp = tile + row * 132 + c4 * 4;
    float4 v = make_float4(tp[0] + hv.x, tp[1] + hv.y, tp[2] + hv.z, tp[3] + hv.w);
    *(float4*)(hbuf + g) = v;
    float ss = v.x * v.x + v.y * v.y + v.z * v.z + v.w * v.w;
    ss += __shfl_xor(ss, 1);
    ss += __shfl_xor(ss, 2);
    ss += __shfl_xor(ss, 4);
    ss += __shfl_xor(ss, 8);
    ss += __shfl_xor(ss, 16);
    float sc = rsqrtf(ss * (1.f / DM) + 1e-5f);
    float4 w4 = *(const float4*)(nw + c4 * 4);
    float n0v = v.x * sc * w4.x, n1v = v.y * sc * w4.y;
    float n2v = v.z * sc * w4.z, n3v = v.w * sc * w4.w;
    if (of) *(float4*)(of + g) = make_float4(n0v, n1v, n2v, n3v);
    short h0s, l0s, h1s, l1s, h2s, l2s, h3s, l3s;
    split_bits2(n0v, h0s, l0s); split_bits2(n1v, h1s, l1s);
    split_bits2(n2v, h2s, l2s); split_bits2(n3v, h3s, l3s);
    bf16x4s hb, lb;
    hb[0] = h0s; hb[1] = h1s; hb[2] = h2s; hb[3] = h3s;
    lb[0] = l0s; lb[1] = l1s; lb[2] = l2s; lb[3] = l3s;
    *(bf16x4s*)(oh + g) = hb;
    *(bf16x4s*)(ol + g) = lb;
  }
}

// ---------------------------------------------------------------------------
// Pooling (deterministic) + classifier
// ---------------------------------------------------------------------------
__global__ __launch_bounds__(256) void pool_partial(const float* __restrict__ fn,
    float* __restrict__ partial) {
  __shared__ float red[256];
  int b = blockIdx.x, c = blockIdx.y;
  int tid = threadIdx.x;
  int d = tid & 127, rp_ = tid >> 7;
  float s = 0.f;
  size_t base = (size_t)b * LL + c * 256;
  for (int i = 0; i < 128; i++) {
    int row = i * 2 + rp_;
    s += fn[(base + row) * DM + d];
  }
  red[tid] = s;
  __syncthreads();
  if (tid < 128) partial[((size_t)b * 8 + c) * 128 + tid] = red[tid] + red[tid + 128];
}

__global__ void pool_reduce(const float* __restrict__ partial,
    float* __restrict__ pooled) {
  int idx = blockIdx.x * 256 + threadIdx.x;   // 2048
  int b = idx >> 7, d = idx & 127;
  float s = 0.f;
#pragma unroll
  for (int c = 0; c < 8; c++) s += partial[((size_t)b * 8 + c) * 128 + d];
  pooled[idx] = s * (1.f / LL);
}

__global__ void cls_kernel(const float* __restrict__ pooled,
    const float* __restrict__ cw, const float* __restrict__ cb,
    float* __restrict__ out) {
  int t = threadIdx.x;
  if (t < 80) {
    int b = t / 5, c = t % 5;
    float acc = cb[c];
    for (int d = 0; d < DM; d++) acc += pooled[b * DM + d] * cw[c * DM + d];
    out[t] = acc;
  }
}

// ---------------------------------------------------------------------------
extern "C" void kernel_launch(void* const* d_in, const int* in_sizes, int n_in,
                              void* d_out, int out_size, void* d_ws, size_t ws_size,
                              hipStream_t stream) {
  const float* x         = (const float*)d_in[0];
  const float* enc_w     = (const float*)d_in[1];
  const float* enc_b     = (const float*)d_in[2];
  const float* norm_w    = (const float*)d_in[3];
  const float* in_proj_w = (const float*)d_in[4];
  const float* conv_w    = (const float*)d_in[5];
  const float* conv_b    = (const float*)d_in[6];
  const float* x_proj_w  = (const float*)d_in[7];
  const float* dt_proj_w = (const float*)d_in[8];
  const float* dt_proj_b = (const float*)d_in[9];
  const float* A_log     = (const float*)d_in[10];
  const float* Dp        = (const float*)d_in[11];
  const float* out_proj_w= (const float*)d_in[12];
  const float* norm_f_w  = (const float*)d_in[13];
  const float* cls_w     = (const float*)d_in[14];
  const float* cls_b     = (const float*)d_in[15];
  float* out = (float*)d_out;

  float* ws = (float*)d_ws;
  float* h       = ws;                       // 4,194,304
  float* xdbl    = ws + 4194304;             // 2,097,152
  float* sega    = ws + 6291456;             // 4,194,304
  float* segh    = ws + 10485760;            // 4,194,304
  uint*  zs_pk   = (uint*)(ws + 14680064);   // 8,388,608
  uint*  u_pk    = (uint*)(ws + 23068672);   // 8,388,608
  uint*  xm_pk   = (uint*)(ws + 31457280);   // 8,388,608
  float* partial = ws + 39845888;            // 16,384
  float* pooled  = ws + 39862272;            // 2,048
  bf16* u0     = (bf16*)(ws + 39864320);
  bf16* xn_hi  = u0;                         // MP*128
  bf16* xn_lo  = u0 + 4194304;
  bf16* wip_hi = u0 + 8388608;               // 262,144
  bf16* wip_lo = wip_hi + 262144;
  bf16* wxp_hi = wip_lo + 262144;            // 65,536 (padded)
  bf16* wxp_lo = wxp_hi + 65536;
  bf16* wop_hi = wxp_lo + 65536;             // 131,072
  bf16* wop_lo = wop_hi + 131072;
  float* fnorm = (float*)xm_pk;              // xm dead after layer-3 gemm_conv

  split_w<<<1024, 256, 0, stream>>>(in_proj_w, wip_hi, wip_lo, 262144);
  split_w_pad<<<256, 256, 0, stream>>>(x_proj_w, wxp_hi, wxp_lo);
  split_w<<<512, 256, 0, stream>>>(out_proj_w, wop_hi, wop_lo, 131072);

  encoder_kernel<<<MP * DM / 256, 256, 0, stream>>>(x, enc_w, enc_b, h);
  rmsnorm_kernel<<<MP / 4, 256, 0, stream>>>(h, norm_w, xn_hi, xn_lo);

  for (int i = 0; i < 4; i++) {
    gemm_inproj<<<MP / 16, 256, 0, stream>>>(xn_hi, xn_lo,
        wip_hi + i * 65536, wip_lo + i * 65536, xm_pk, zs_pk);
    gemm_conv<<<MP / 64, 256, 0, stream>>>(xm_pk,
        wxp_hi + i * 16384, wxp_lo + i * 16384,
        conv_w + i * DI * 4, conv_b + i * DI, xdbl, u_pk);
    scan_phase1<<<dim3(NSEG, BB), 256, 0, stream>>>(u_pk, xdbl,
        dt_proj_w + i * 2048, dt_proj_b + i * DI, A_log + i * DI * DS, sega, segh);
    scan_combine<<<64, 256, 0, stream>>>(sega, segh);
    scan2_outproj<<<dim3(NSEG, BB), 256, 0, stream>>>(u_pk, zs_pk, xdbl,
        dt_proj_w + i * 2048, dt_proj_b + i * DI, A_log + i * DI * DS,
        Dp + i * DI, sega, wop_hi + i * 32768, wop_lo + i * 32768, h,
        (i < 3) ? norm_w + (i + 1) * DM : norm_f_w,
        (i < 3) ? nullptr : fnorm, xn_hi, xn_lo);
  }

  pool_partial<<<dim3(BB, 8), 256, 0, stream>>>(fnorm, partial);
  pool_reduce<<<8, 256, 0, stream>>>(partial, pooled);
  cls_kernel<<<1, 128, 0, stream>>>(pooled, cls_w, cls_b, out);
}

// Round 20
// 773.727 us; speedup vs baseline: 1.3745x; 1.0339x over previous
//
#include <hip/hip_runtime.h>
#include <hip/hip_bf16.h>
#include <cstddef>

#define BB 16
#define LL 2048
#define DM 128
#define DI 256
#define DS 16
#define MP (BB*LL)          // 32768 positions
#define NSEG 64
#define SEGLEN (LL/NSEG)    // 32
#define YSTR 264            // ybuf LDS row stride (shorts): 16B-aligned rows, uniform bank spread
#define XSTR 40             // sx LDS row stride (floats)

typedef __attribute__((ext_vector_type(8))) short bf16x8;
typedef __attribute__((ext_vector_type(4))) short bf16x4s;
typedef __attribute__((ext_vector_type(8))) unsigned int ux8;
typedef __attribute__((ext_vector_type(4))) float f32x4;
typedef __hip_bfloat16 bf16;
typedef unsigned int uint;

__device__ inline void bf16split(float x, bf16& h, bf16& l) {
  h = __float2bfloat16(x);
  l = __float2bfloat16(x - __bfloat162float(h));
}
__device__ inline float bf2f(bf16 v) { return __bfloat162float(v); }
__device__ inline void split_bits2(float x, short& hs, short& ls) {
  bf16 hb = __float2bfloat16(x);
  bf16 lb = __float2bfloat16(x - __bfloat162float(hb));
  hs = *(short*)&hb;
  ls = *(short*)&lb;
}
__device__ inline short bfbits(float x) {
  bf16 b = __float2bfloat16(x);
  return *(short*)&b;
}
__device__ inline float sigm(float x) {
  return __builtin_amdgcn_rcpf(1.f + __expf(-x));
}
__device__ inline uint pk2(short h, short l) {
  return (uint)(unsigned short)h | ((uint)(unsigned short)l << 16);
}
__device__ inline uint pack_hl(float x) {
  short hs, ls; split_bits2(x, hs, ls);
  return pk2(hs, ls);
}
__device__ inline float unpack_hl(uint w) {
  return __uint_as_float(w << 16) + __uint_as_float(w & 0xffff0000u);
}

// ---------------------------------------------------------------------------
// in_proj: block = 32 positions x 256 cols. Packed dword outputs, no LDS.
// ---------------------------------------------------------------------------
__global__ __launch_bounds__(256, 4) void gemm_inproj(
    const bf16* __restrict__ Ah, const bf16* __restrict__ Al,
    const bf16* __restrict__ Wh, const bf16* __restrict__ Wl,
    uint* __restrict__ xm_pk, uint* __restrict__ zs_pk) {
  int tid = threadIdx.x;
  int wave = tid >> 6, lane = tid & 63;
  int r16 = lane & 15, quad = lane >> 4;
  int bid = blockIdx.x;
  int nh = bid & 1, mb = bid >> 1;
  int m0 = mb * 32;
  int n0 = nh * 256 + wave * 64;
  size_t arow[2], brow[4];
#pragma unroll
  for (int i = 0; i < 2; i++)
    arow[i] = (size_t)(m0 + i * 16 + r16) * DM + quad * 8;
#pragma unroll
  for (int j = 0; j < 4; j++)
    brow[j] = (size_t)(n0 + j * 16 + r16) * DM + quad * 8;
  f32x4 acc[2][4] = {};
#pragma unroll
  for (int kk = 0; kk < 4; kk++) {
    int ko = kk * 32;
    bf16x8 ah[2], al[2], bh[4], bl[4];
#pragma unroll
    for (int i = 0; i < 2; i++) {
      ah[i] = *(const bf16x8*)(Ah + arow[i] + ko);
      al[i] = *(const bf16x8*)(Al + arow[i] + ko);
    }
#pragma unroll
    for (int j = 0; j < 4; j++) {
      bh[j] = *(const bf16x8*)(Wh + brow[j] + ko);
      bl[j] = *(const bf16x8*)(Wl + brow[j] + ko);
    }
#pragma unroll
    for (int i = 0; i < 2; i++)
#pragma unroll
      for (int j = 0; j < 4; j++) {
        acc[i][j] = __builtin_amdgcn_mfma_f32_16x16x32_bf16(ah[i], bh[j], acc[i][j], 0, 0, 0);
        acc[i][j] = __builtin_amdgcn_mfma_f32_16x16x32_bf16(ah[i], bl[j], acc[i][j], 0, 0, 0);
        acc[i][j] = __builtin_amdgcn_mfma_f32_16x16x32_bf16(al[i], bh[j], acc[i][j], 0, 0, 0);
      }
  }
  bool isz = (n0 >= 256);
  uint* dst = isz ? zs_pk : xm_pk;
  int cb = n0 & 255;
#pragma unroll
  for (int i = 0; i < 2; i++)
#pragma unroll
    for (int j = 0; j < 4; j++)
#pragma unroll
      for (int r = 0; r < 4; r++) {
        int row = m0 + i * 16 + quad * 4 + r;
        int col = cb + j * 16 + r16;
        float v = acc[i][j][r];
        if (isz) v *= sigm(v);
        dst[(size_t)row * DI + col] = pack_hl(v);
      }
}

// ---------------------------------------------------------------------------
// x_proj with fused conv+SiLU. Wave owns a distinct 16-row m-tile x 48 cols.
// ---------------------------------------------------------------------------
__global__ __launch_bounds__(256, 2) void gemm_conv(
    const uint* __restrict__ xm_pk,
    const bf16* __restrict__ Wh, const bf16* __restrict__ Wl,
    const float* __restrict__ cw, const float* __restrict__ cb,
    float* __restrict__ C, uint* __restrict__ u_pk) {
  __shared__ float scw[DI * 4 + DI];
  int tid = threadIdx.x;
  {
    float4 w4 = *(const float4*)(cw + tid * 4);
    *(float4*)(scw + tid * 4) = w4;
    scw[DI * 4 + tid] = cb[tid];
  }
  __syncthreads();
  int wave = tid >> 6, lane = tid & 63;
  int r16 = lane & 15, quad = lane >> 4;
  int m0 = blockIdx.x * 64 + wave * 16;
  int m = m0 + r16;
  int l = m & (LL - 1);
  size_t rb[4]; float msk[3];
#pragma unroll
  for (int t = 0; t < 3; t++) {
    msk[t] = (l >= (3 - t)) ? 1.f : 0.f;
    int mr = m - 3 + t; if (mr < 0) mr = 0;
    rb[t] = (size_t)mr * DI;
  }
  rb[3] = (size_t)m * DI;
  size_t brow[3];
#pragma unroll
  for (int j = 0; j < 3; j++)
    brow[j] = (size_t)(j * 16 + r16) * DI + quad * 8;
  f32x4 acc[3] = {};
#pragma unroll
  for (int kk = 0; kk < 8; kk++) {
    int ko = quad * 8 + kk * 32;
    bf16x8 ah, al, bh[3], bl[3];
    ux8 xv[4];
#pragma unroll
    for (int t = 0; t < 4; t++)
      xv[t] = *(const ux8*)(xm_pk + rb[t] + ko);
#pragma unroll
    for (int e = 0; e < 8; e++) {
      int k = ko + e;
      float x0 = unpack_hl(xv[0][e]) * msk[0];
      float x1 = unpack_hl(xv[1][e]) * msk[1];
      float x2 = unpack_hl(xv[2][e]) * msk[2];
      float x3 = unpack_hl(xv[3][e]);
      float c0 = scw[DI * 4 + k] + scw[k*4]*x0 + scw[k*4+1]*x1 + scw[k*4+2]*x2 + scw[k*4+3]*x3;
      float u = c0 * sigm(c0);
      short hs, ls; split_bits2(u, hs, ls);
      ah[e] = hs; al[e] = ls;
    }
    {
      size_t g = rb[3] + ko;
      uint4 p0, p1;
      p0.x = pk2(ah[0], al[0]); p0.y = pk2(ah[1], al[1]);
      p0.z = pk2(ah[2], al[2]); p0.w = pk2(ah[3], al[3]);
      p1.x = pk2(ah[4], al[4]); p1.y = pk2(ah[5], al[5]);
      p1.z = pk2(ah[6], al[6]); p1.w = pk2(ah[7], al[7]);
      *(uint4*)(u_pk + g) = p0;
      *(uint4*)(u_pk + g + 4) = p1;
    }
#pragma unroll
    for (int j = 0; j < 3; j++) {
      bh[j] = *(const bf16x8*)(Wh + brow[j] + kk * 32);
      bl[j] = *(const bf16x8*)(Wl + brow[j] + kk * 32);
    }
#pragma unroll
    for (int j = 0; j < 3; j++) {
      acc[j] = __builtin_amdgcn_mfma_f32_16x16x32_bf16(ah, bh[j], acc[j], 0, 0, 0);
      acc[j] = __builtin_amdgcn_mfma_f32_16x16x32_bf16(ah, bl[j], acc[j], 0, 0, 0);
      acc[j] = __builtin_amdgcn_mfma_f32_16x16x32_bf16(al, bh[j], acc[j], 0, 0, 0);
    }
  }
#pragma unroll
  for (int j = 0; j < 3; j++)
#pragma unroll
    for (int r = 0; r < 4; r++) {
      int row = m0 + quad * 4 + r;
      int col = j * 16 + r16;
      C[(size_t)row * 64 + col] = acc[j][r];
    }
}

// ---------------------------------------------------------------------------
// Encoder (K=12, direct)
// ---------------------------------------------------------------------------
__global__ __launch_bounds__(256) void encoder_kernel(const float* __restrict__ x,
    const float* __restrict__ ew, const float* __restrict__ eb,
    float* __restrict__ h) {
  int idx = blockIdx.x * 256 + threadIdx.x;
  int d = idx & 127, m = idx >> 7;
  float acc = eb[d];
#pragma unroll
  for (int c = 0; c < 12; c++) acc += x[m * 12 + c] * ew[d * 12 + c];
  h[idx] = acc;
}

// ---------------------------------------------------------------------------
// Weight splits
// ---------------------------------------------------------------------------
__global__ void split_w(const float* __restrict__ src, bf16* __restrict__ hi,
                        bf16* __restrict__ lo, int n) {
  int i = blockIdx.x * 256 + threadIdx.x;
  if (i < n) bf16split(src[i], hi[i], lo[i]);
}

__global__ void split_w_pad(const float* __restrict__ src, bf16* __restrict__ hi,
                            bf16* __restrict__ lo) {
  int i = blockIdx.x * 256 + threadIdx.x;   // < 4*64*256
  int l = i >> 14, rem = i & 16383, r = rem >> 8, k = rem & 255;
  float v = (r < 40) ? src[l * 10240 + r * 256 + k] : 0.f;
  bf16split(v, hi[i], lo[i]);
}

// ---------------------------------------------------------------------------
// RMSNorm (layer-0 input only)
// ---------------------------------------------------------------------------
__global__ __launch_bounds__(256) void rmsnorm_kernel(const float* __restrict__ x,
    const float* __restrict__ w, bf16* __restrict__ oh, bf16* __restrict__ ol) {
  int lane = threadIdx.x & 63;
  int pos = blockIdx.x * 4 + (threadIdx.x >> 6);
  const float* row = x + (size_t)pos * DM;
  float v0 = row[lane], v1 = row[lane + 64];
  float ss = v0 * v0 + v1 * v1;
#pragma unroll
  for (int off = 1; off < 64; off <<= 1) ss += __shfl_xor(ss, off);
  float sc = rsqrtf(ss * (1.f / DM) + 1e-5f);
  float a = v0 * sc * w[lane], b = v1 * sc * w[lane + 64];
  size_t o = (size_t)pos * DM;
  bf16split(a, oh[o + lane], ol[o + lane]);
  bf16split(b, oh[o + lane + 64], ol[o + lane + 64]);
}

// ---------------------------------------------------------------------------
// Scan helpers
// ---------------------------------------------------------------------------
__device__ inline float softplus_f(float a) {
  float r = __logf(1.f + __expf(a));
  return a > 15.f ? a : r;
}

__device__ inline void make_powers(float r, float* rp) {
  rp[0] = r;
#pragma unroll
  for (int n = 1; n < 16; n++) {
    int a = (n + 1) >> 1, b = (n + 1) - a;
    rp[n] = rp[a - 1] * rp[b - 1];
  }
}

__device__ inline bool a_is_integer(const float* A_log, int d) {
  bool ok = true;
#pragma unroll
  for (int n = 0; n < DS; n++) {
    float Ad = -__expf(A_log[d * DS + n]);
    ok = ok && (fabsf(Ad + (float)(n + 1)) < 1e-3f);
  }
  return ok;
}

// load 32 rows x 40 cols of xdbl (cols 0..39) into LDS, stride XSTR
__device__ inline void load_sx(float* sx, const float* xdbl, size_t rbase, int tid) {
#pragma unroll
  for (int j = 0; j < 2; j++) {
    int idx = j * 256 + tid;       // < 320 = 32 rows x 10 float4
    if (idx < 320) {
      int row = idx / 10, c = idx % 10;
      *(float4*)(sx + row * XSTR + c * 4) = *(const float4*)(xdbl + rbase + row * 64 + c * 4);
    }
  }
}

template<bool FAST>
__device__ inline void scan1_body(int s, int b, int d, const float* sx,
    const uint* __restrict__ u_pk,
    const float* __restrict__ dtw, const float* __restrict__ dtb,
    const float* __restrict__ A_log,
    float* __restrict__ sega, float* __restrict__ segh) {
  float wdt[8];
#pragma unroll
  for (int j = 0; j < 8; j++) wdt[j] = dtw[d * 8 + j];
  float bdt = dtb[d];
  float h[DS];
#pragma unroll
  for (int n = 0; n < DS; n++) h[n] = 0.f;
  float R = 1.f;
  float ap[DS];
  if (!FAST) {
#pragma unroll
    for (int n = 0; n < DS; n++) ap[n] = 1.f;
  }
  size_t base = (size_t)b * LL + (size_t)s * SEGLEN;
  const uint* up = u_pk + base * DI + d;
  uint ub = *up;
#pragma unroll 4
  for (int t = 0; t < SEGLEN; t++) {
    up += DI;
    uint ub_next = *up;
    const float* xr = sx + t * XSTR;
    float dt = bdt;
#pragma unroll
    for (int j = 0; j < 8; j++) dt += xr[j] * wdt[j];
    float dl = softplus_f(dt);
    float u = unpack_hl(ub);
    float du = dl * u;
    if (FAST) {
      float rp[DS];
      make_powers(__expf(-dl), rp);
      R *= rp[0];
#pragma unroll
      for (int n = 0; n < DS; n++) h[n] = fmaf(rp[n], h[n], du * xr[8 + n]);
    } else {
#pragma unroll
      for (int n = 0; n < DS; n++) {
        float dA = __expf(dl * (-__expf(A_log[d * DS + n])));
        h[n] = fmaf(dA, h[n], du * xr[8 + n]);
        ap[n] *= dA;
      }
    }
    ub = ub_next;
  }
  if (FAST) make_powers(R, ap);
  size_t o = ((size_t)s * 4096 + b * 256 + d) * DS;
#pragma unroll
  for (int j = 0; j < 4; j++) {
    *(float4*)(sega + o + 4 * j) = make_float4(ap[4*j], ap[4*j+1], ap[4*j+2], ap[4*j+3]);
    *(float4*)(segh + o + 4 * j) = make_float4(h[4*j], h[4*j+1], h[4*j+2], h[4*j+3]);
  }
}

__global__ __launch_bounds__(256, 6) void scan_phase1(
    const uint* __restrict__ u_pk, const float* __restrict__ xdbl,
    const float* __restrict__ dtw, const float* __restrict__ dtb,
    const float* __restrict__ A_log,
    float* __restrict__ sega, float* __restrict__ segh) {
  __shared__ float sx[SEGLEN * XSTR];
  int s = blockIdx.x, b = blockIdx.y, d = threadIdx.x;
  size_t rbase = ((size_t)b * LL + (size_t)s * SEGLEN) * 64;
  load_sx(sx, xdbl, rbase, d);
  __syncthreads();
  if (a_is_integer(A_log, d))
    scan1_body<true>(s, b, d, sx, u_pk, dtw, dtb, A_log, sega, segh);
  else
    scan1_body<false>(s, b, d, sx, u_pk, dtw, dtb, A_log, sega, segh);
}

__global__ __launch_bounds__(256) void scan_combine(float* __restrict__ sega,
    const float* __restrict__ segh) {
  int g = blockIdx.x * 256 + threadIdx.x;
  size_t off = (size_t)(g >> 2) * 16 + (g & 3) * 4;
  float4 h0 = make_float4(0.f, 0.f, 0.f, 0.f);
  for (int s = 0; s < NSEG; s++) {
    size_t q = (size_t)s * 65536 + off;
    float4 a = *(float4*)(sega + q);
    float4 hh = *(float4*)(segh + q);
    *(float4*)(sega + q) = h0;
    h0.x = a.x * h0.x + hh.x;
    h0.y = a.y * h0.y + hh.y;
    h0.z = a.z * h0.z + hh.z;
    h0.w = a.w * h0.w + hh.w;
  }
}

// ---------------------------------------------------------------------------
// FUSED scan_phase2 + out_proj + residual + RMSNorm (NSEG=64, 32-row tile).
// y staged in LDS as plain bf16 shorts (16.9 KB) -> ~7 blocks/CU; out_proj
// A-frags are direct bf16x8 LDS reads (no unpack) with 2 MFMAs per frag.
// ---------------------------------------------------------------------------
template<bool FAST>
__device__ inline void scan2_to_lds(int s, int b, int d, const float* sx,
    const uint* __restrict__ u_pk, const uint* __restrict__ zs_pk,
    const float* __restrict__ dtw, const float* __restrict__ dtb,
    const float* __restrict__ A_log, const float* __restrict__ Dp,
    const float* __restrict__ sega, short* __restrict__ ybuf) {
  float wdt[8];
#pragma unroll
  for (int j = 0; j < 8; j++) wdt[j] = dtw[d * 8 + j];
  float bdt = dtb[d];
  float h[DS];
  size_t o = ((size_t)s * 4096 + b * 256 + d) * DS;
#pragma unroll
  for (int n = 0; n < DS; n++) h[n] = sega[o + n];
  float Dd = Dp[d];
  size_t base = (size_t)b * LL + (size_t)s * SEGLEN;
  const uint* up = u_pk + base * DI + d;
  const uint* zp = zs_pk + base * DI + d;
  uint ub = *up, zb = *zp;
#pragma unroll 4
  for (int t = 0; t < SEGLEN; t++) {
    up += DI; zp += DI;
    uint ub_next = *up;
    uint zb_next = *zp;
    const float* xr = sx + t * XSTR;
    float dt = bdt;
#pragma unroll
    for (int j = 0; j < 8; j++) dt += xr[j] * wdt[j];
    float dl = softplus_f(dt);
    float u = unpack_hl(ub);
    float du = dl * u;
    float acc = 0.f;
    if (FAST) {
      float rp[DS];
      make_powers(__expf(-dl), rp);
#pragma unroll
      for (int n = 0; n < DS; n++) {
        h[n] = fmaf(rp[n], h[n], du * xr[8 + n]);
        acc = fmaf(h[n], xr[24 + n], acc);
      }
    } else {
#pragma unroll
      for (int n = 0; n < DS; n++) {
        float dA = __expf(dl * (-__expf(A_log[d * DS + n])));
        h[n] = fmaf(dA, h[n], du * xr[8 + n]);
        acc = fmaf(h[n], xr[24 + n], acc);
      }
    }
    float zs = unpack_hl(zb);
    float yv = (acc + u * Dd) * zs;
    ybuf[t * YSTR + d] = bfbits(yv);
    ub = ub_next; zb = zb_next;
  }
}

__global__ __launch_bounds__(256, 6) void scan2_outproj(
    const uint* __restrict__ u_pk, const uint* __restrict__ zs_pk,
    const float* __restrict__ xdbl, const float* __restrict__ dtw,
    const float* __restrict__ dtb, const float* __restrict__ A_log,
    const float* __restrict__ Dp, const float* __restrict__ sega,
    const bf16* __restrict__ Wh, const bf16* __restrict__ Wl,
    float* __restrict__ hbuf, const float* __restrict__ nw,
    float* __restrict__ of, bf16* __restrict__ oh, bf16* __restrict__ ol) {
  __shared__ float sx[SEGLEN * XSTR];      // 5 KB
  __shared__ short ybuf[32 * YSTR];        // 16.9 KB (bf16 y; later fp32 tile)
  int s = blockIdx.x, b = blockIdx.y;
  int tid = threadIdx.x, d = tid;
  size_t rbase = ((size_t)b * LL + (size_t)s * SEGLEN) * 64;
  load_sx(sx, xdbl, rbase, tid);
  __syncthreads();
  if (a_is_integer(A_log, d))
    scan2_to_lds<true>(s, b, d, sx, u_pk, zs_pk, dtw, dtb, A_log, Dp, sega, ybuf);
  else
    scan2_to_lds<false>(s, b, d, sx, u_pk, zs_pk, dtw, dtb, A_log, Dp, sega, ybuf);
  __syncthreads();
  // out_proj: C[32x128] = y[32x256] @ Wop[128x256]^T, wave covers 32 cols
  int wave = tid >> 6, lane = tid & 63;
  int r16 = lane & 15, quad = lane >> 4;
  int n0 = wave * 32;
  size_t brow[2];
#pragma unroll
  for (int j = 0; j < 2; j++)
    brow[j] = (size_t)(n0 + j * 16 + r16) * DI + quad * 8;
  f32x4 acc[2][2] = {};
#pragma unroll
  for (int kk = 0; kk < 8; kk++) {
    int k0 = quad * 8 + kk * 32;
    bf16x8 ah[2], bh[2], bl[2];
#pragma unroll
    for (int i = 0; i < 2; i++)
      ah[i] = *(const bf16x8*)(ybuf + (i * 16 + r16) * YSTR + k0);
#pragma unroll
    for (int j = 0; j < 2; j++) {
      bh[j] = *(const bf16x8*)(Wh + brow[j] + kk * 32);
      bl[j] = *(const bf16x8*)(Wl + brow[j] + kk * 32);
    }
#pragma unroll
    for (int i = 0; i < 2; i++)
#pragma unroll
      for (int j = 0; j < 2; j++) {
        acc[i][j] = __builtin_amdgcn_mfma_f32_16x16x32_bf16(ah[i], bh[j], acc[i][j], 0, 0, 0);
        acc[i][j] = __builtin_amdgcn_mfma_f32_16x16x32_bf16(ah[i], bl[j], acc[i][j], 0, 0, 0);
      }
  }
  __syncthreads();   // all LDS y reads done; reuse ybuf as fp32 tile 32x132
  float* tile = (float*)ybuf;
#pragma unroll
  for (int i = 0; i < 2; i++)
#pragma unroll
    for (int j = 0; j < 2; j++)
#pragma unroll
      for (int r = 0; r < 4; r++) {
        int rl = i * 16 + quad * 4 + r;
        int col = n0 + j * 16 + r16;
        tile[rl * 132 + col] = acc[i][j][r];
      }
  __syncthreads();
  // epilogue: residual + rmsnorm + bf16 split, coalesced
  size_t mbase = (size_t)b * LL + (size_t)s * SEGLEN;
#pragma unroll
  for (int it = 0; it < 4; it++) {
    int idx = it * 256 + tid;
    int row = idx >> 5, c4 = idx & 31;
    size_t g = (mbase + row) * DM + c4 * 4;
    float4 hv = *(float4*)(hbuf + g);
    const float* tp = tile + row * 132 + c4 * 4;
    float4 v = make_float4(tp[0] + hv.x, tp[1] + hv.y, tp[2] + hv.z, tp[3] + hv.w);
    *(float4*)(hbuf + g) = v;
    float ss = v.x * v.x + v.y * v.y + v.z * v.z + v.w * v.w;
    ss += __shfl_xor(ss, 1);
    ss += __shfl_xor(ss, 2);
    ss += __shfl_xor(ss, 4);
    ss += __shfl_xor(ss, 8);
    ss += __shfl_xor(ss, 16);
    float sc = rsqrtf(ss * (1.f / DM) + 1e-5f);
    float4 w4 = *(const float4*)(nw + c4 * 4);
    float n0v = v.x * sc * w4.x, n1v = v.y * sc * w4.y;
    float n2v = v.z * sc * w4.z, n3v = v.w * sc * w4.w;
    if (of) *(float4*)(of + g) = make_float4(n0v, n1v, n2v, n3v);
    short h0s, l0s, h1s, l1s, h2s, l2s, h3s, l3s;
    split_bits2(n0v, h0s, l0s); split_bits2(n1v, h1s, l1s);
    split_bits2(n2v, h2s, l2s); split_bits2(n3v, h3s, l3s);
    bf16x4s hb, lb;
    hb[0] = h0s; hb[1] = h1s; hb[2] = h2s; hb[3] = h3s;
    lb[0] = l0s; lb[1] = l1s; lb[2] = l2s; lb[3] = l3s;
    *(bf16x4s*)(oh + g) = hb;
    *(bf16x4s*)(ol + g) = lb;
  }
}

// ---------------------------------------------------------------------------
// Pooling (deterministic) + classifier
// ---------------------------------------------------------------------------
__global__ __launch_bounds__(256) void pool_partial(const float* __restrict__ fn,
    float* __restrict__ partial) {
  __shared__ float red[256];
  int b = blockIdx.x, c = blockIdx.y;
  int tid = threadIdx.x;
  int d = tid & 127, rp_ = tid >> 7;
  float s = 0.f;
  size_t base = (size_t)b * LL + c * 256;
  for (int i = 0; i < 128; i++) {
    int row = i * 2 + rp_;
    s += fn[(base + row) * DM + d];
  }
  red[tid] = s;
  __syncthreads();
  if (tid < 128) partial[((size_t)b * 8 + c) * 128 + tid] = red[tid] + red[tid + 128];
}

__global__ void pool_reduce(const float* __restrict__ partial,
    float* __restrict__ pooled) {
  int idx = blockIdx.x * 256 + threadIdx.x;   // 2048
  int b = idx >> 7, d = idx & 127;
  float s = 0.f;
#pragma unroll
  for (int c = 0; c < 8; c++) s += partial[((size_t)b * 8 + c) * 128 + d];
  pooled[idx] = s * (1.f / LL);
}

__global__ void cls_kernel(const float* __restrict__ pooled,
    const float* __restrict__ cw, const float* __restrict__ cb,
    float* __restrict__ out) {
  int t = threadIdx.x;
  if (t < 80) {
    int b = t / 5, c = t % 5;
    float acc = cb[c];
    for (int d = 0; d < DM; d++) acc += pooled[b * DM + d] * cw[c * DM + d];
    out[t] = acc;
  }
}

// ---------------------------------------------------------------------------
extern "C" void kernel_launch(void* const* d_in, const int* in_sizes, int n_in,
                              void* d_out, int out_size, void* d_ws, size_t ws_size,
                              hipStream_t stream) {
  const float* x         = (const float*)d_in[0];
  const float* enc_w     = (const float*)d_in[1];
  const float* enc_b     = (const float*)d_in[2];
  const float* norm_w    = (const float*)d_in[3];
  const float* in_proj_w = (const float*)d_in[4];
  const float* conv_w    = (const float*)d_in[5];
  const float* conv_b    = (const float*)d_in[6];
  const float* x_proj_w  = (const float*)d_in[7];
  const float* dt_proj_w = (const float*)d_in[8];
  const float* dt_proj_b = (const float*)d_in[9];
  const float* A_log     = (const float*)d_in[10];
  const float* Dp        = (const float*)d_in[11];
  const float* out_proj_w= (const float*)d_in[12];
  const float* norm_f_w  = (const float*)d_in[13];
  const float* cls_w     = (const float*)d_in[14];
  const float* cls_b     = (const float*)d_in[15];
  float* out = (float*)d_out;

  float* ws = (float*)d_ws;
  float* h       = ws;                       // 4,194,304
  float* xdbl    = ws + 4194304;             // 2,097,152
  float* sega    = ws + 6291456;             // 4,194,304
  float* segh    = ws + 10485760;            // 4,194,304
  uint*  zs_pk   = (uint*)(ws + 14680064);   // 8,388,608
  uint*  u_pk    = (uint*)(ws + 23068672);   // 8,388,608
  uint*  xm_pk   = (uint*)(ws + 31457280);   // 8,388,608
  float* partial = ws + 39845888;            // 16,384
  float* pooled  = ws + 39862272;            // 2,048
  bf16* u0     = (bf16*)(ws + 39864320);
  bf16* xn_hi  = u0;                         // MP*128
  bf16* xn_lo  = u0 + 4194304;
  bf16* wip_hi = u0 + 8388608;               // 262,144
  bf16* wip_lo = wip_hi + 262144;
  bf16* wxp_hi = wip_lo + 262144;            // 65,536 (padded)
  bf16* wxp_lo = wxp_hi + 65536;
  bf16* wop_hi = wxp_lo + 65536;             // 131,072
  bf16* wop_lo = wop_hi + 131072;
  float* fnorm = (float*)xm_pk;              // xm dead after layer-3 gemm_conv

  split_w<<<1024, 256, 0, stream>>>(in_proj_w, wip_hi, wip_lo, 262144);
  split_w_pad<<<256, 256, 0, stream>>>(x_proj_w, wxp_hi, wxp_lo);
  split_w<<<512, 256, 0, stream>>>(out_proj_w, wop_hi, wop_lo, 131072);

  encoder_kernel<<<MP * DM / 256, 256, 0, stream>>>(x, enc_w, enc_b, h);
  rmsnorm_kernel<<<MP / 4, 256, 0, stream>>>(h, norm_w, xn_hi, xn_lo);

  for (int i = 0; i < 4; i++) {
    gemm_inproj<<<MP / 16, 256, 0, stream>>>(xn_hi, xn_lo,
        wip_hi + i * 65536, wip_lo + i * 65536, xm_pk, zs_pk);
    gemm_conv<<<MP / 64, 256, 0, stream>>>(xm_pk,
        wxp_hi + i * 16384, wxp_lo + i * 16384,
        conv_w + i * DI * 4, conv_b + i * DI, xdbl, u_pk);
    scan_phase1<<<dim3(NSEG, BB), 256, 0, stream>>>(u_pk, xdbl,
        dt_proj_w + i * 2048, dt_proj_b + i * DI, A_log + i * DI * DS, sega, segh);
    scan_combine<<<64, 256, 0, stream>>>(sega, segh);
    scan2_outproj<<<dim3(NSEG, BB), 256, 0, stream>>>(u_pk, zs_pk, xdbl,
        dt_proj_w + i * 2048, dt_proj_b + i * DI, A_log + i * DI * DS,
        Dp + i * DI, sega, wop_hi + i * 32768, wop_lo + i * 32768, h,
        (i < 3) ? norm_w + (i + 1) * DM : norm_f_w,
        (i < 3) ? nullptr : fnorm, xn_hi, xn_lo);
  }

  pool_partial<<<dim3(BB, 8), 256, 0, stream>>>(fnorm, partial);
  pool_reduce<<<8, 256, 0, stream>>>(partial, pooled);
  cls_kernel<<<1, 128, 0, stream>>>(pooled, cls_w, cls_b, out);
}